// Round 3
// baseline (265.361 us; speedup 1.0000x reference)
//
#include <hip/hip_runtime.h>
#include <hip/hip_bf16.h>

#define N_POINTS 262144
#define SP_FEAT 128
#define HIDDEN 64
#define EMBED 256
#define NUM_SP 4096
#define NUM_SP2 256
#define PAD_LIMIT 64

typedef __bf16 bf16x8 __attribute__((ext_vector_type(8)));
typedef float floatx4 __attribute__((ext_vector_type(4)));
using bf16 = __hip_bfloat16;

// ---------------------------------------------------------------------------
// Prep: transpose + cvt weights (W1t [64][128], W2t [256][64] bf16) and
// start[s] = lower_bound(idx10, s) for s in [0,4096], start[4096]=N_POINTS.
// ---------------------------------------------------------------------------
__global__ void prep_kernel(const float* __restrict__ W1, const float* __restrict__ W2,
                            const int* __restrict__ idx10,
                            bf16* __restrict__ W1t, bf16* __restrict__ W2t,
                            int* __restrict__ start) {
    int i = blockIdx.x * blockDim.x + threadIdx.x;
    if (i < HIDDEN * SP_FEAT) {
        int n = i >> 7, k = i & 127;
        W1t[i] = __float2bfloat16(W1[k * HIDDEN + n]);
    } else if (i < HIDDEN * SP_FEAT + EMBED * HIDDEN) {
        int j = i - HIDDEN * SP_FEAT;
        int n = j >> 6, k = j & 63;
        W2t[j] = __float2bfloat16(W2[k * EMBED + n]);
    } else if (i <= HIDDEN * SP_FEAT + EMBED * HIDDEN + NUM_SP) {
        int s = i - (HIDDEN * SP_FEAT + EMBED * HIDDEN);
        if (s == NUM_SP) { start[s] = N_POINTS; return; }
        int a = 0, b = N_POINTS;
        while (a < b) { int m = (a + b) >> 1; if (idx10[m] < s) a = m + 1; else b = m; }
        start[s] = a;
    }
}

// ---------------------------------------------------------------------------
// Rank tables: invR/invM[g][slot] = superpoint id (or -1) — one block.
// Detects is_masked encoding (byte-bool vs int32) block-wide.
// ---------------------------------------------------------------------------
__global__ __launch_bounds__(256) void rank_kernel(
    const int* __restrict__ idx21, const void* __restrict__ is_masked,
    int* __restrict__ invR, int* __restrict__ invM) {
    __shared__ int encS;
    const int tid = threadIdx.x;
    if (tid == 0) encS = 0;
    __syncthreads();
    const unsigned char* mb = (const unsigned char*)is_masked;
    const int* mi = (const int*)is_masked;
    int local = 0;
    for (int p = tid; p < NUM_SP; p += 256)
        if ((p & 3) && mb[p]) local = 1;
    if (local) atomicOr(&encS, 1);
    __syncthreads();
    const int e = encS;

    const int g = tid;   // sp2 group 0..255
    int a = 0, b = NUM_SP;
    while (a < b) { int m = (a + b) >> 1; if (idx21[m] < g) a = m + 1; else b = m; }
    int lo = a;
    b = NUM_SP;
    while (a < b) { int m = (a + b) >> 1; if (idx21[m] < g + 1) a = m + 1; else b = m; }
    int hi = a;
    int nR = 0, nM = 0;
    for (int s = lo; s < hi; ++s) {
        int msk = e ? (int)mb[s] : mi[s];
        if (msk) { if (nM < PAD_LIMIT) invM[g * PAD_LIMIT + nM] = s; nM++; }
        else     { if (nR < PAD_LIMIT) invR[g * PAD_LIMIT + nR] = s; nR++; }
    }
    for (int r = nR; r < PAD_LIMIT; ++r) invR[g * PAD_LIMIT + r] = -1;
    for (int r = nM; r < PAD_LIMIT; ++r) invM[g * PAD_LIMIT + r] = -1;
}

// ---------------------------------------------------------------------------
// One block per superpoint: MLP over its contiguous point range in 64-row
// tiles, running register max across tiles, one coalesced tok write.
// No atomics. Tail rows clamp to last valid point (same sp => max unchanged).
// ---------------------------------------------------------------------------
__global__ __launch_bounds__(256) void mlp_segmax_kernel(
    const float* __restrict__ X, const int* __restrict__ start,
    const bf16* __restrict__ W1t, const float* __restrict__ b1,
    const bf16* __restrict__ W2t, const float* __restrict__ b2,
    float* __restrict__ tok)
{
    __shared__ __align__(16) bf16 Xs[64][136];   // 272B stride
    __shared__ __align__(16) bf16 H1s[64][72];   // 144B stride
    __shared__ float tokS[EMBED];

    const int tid  = threadIdx.x;
    const int lane = tid & 63;
    const int w    = tid >> 6;
    const int l15  = lane & 15;
    const int quad = lane >> 4;
    const int s    = blockIdx.x;

    const int s0 = start[s];
    int cnt = start[s + 1] - s0;
    if (cnt < 1) cnt = 1;
    const int ntiles = (cnt + 63) >> 6;

    // loop-invariant B-fragments (cache-hot 48 KB)
    bf16x8 bw1[4];
    {
        const bf16* p = W1t + (16 * w + l15) * SP_FEAT + quad * 8;
#pragma unroll
        for (int ks = 0; ks < 4; ++ks) bw1[ks] = *(const bf16x8*)(p + 32 * ks);
    }
    bf16x8 bf2[4][2];
#pragma unroll
    for (int tn = 0; tn < 4; ++tn) {
        const bf16* p = W2t + (64 * w + 16 * tn + l15) * HIDDEN + quad * 8;
#pragma unroll
        for (int ks = 0; ks < 2; ++ks) bf2[tn][ks] = *(const bf16x8*)(p + 32 * ks);
    }
    float b2f[4];
#pragma unroll
    for (int tn = 0; tn < 4; ++tn) b2f[tn] = b2[64 * w + 16 * tn + l15];
    const float b1v = b1[16 * w + l15];

    floatx4 zero4 = {0.f, 0.f, 0.f, 0.f};
    floatx4 macc[4][4];
#pragma unroll
    for (int tm = 0; tm < 4; ++tm)
#pragma unroll
        for (int tn = 0; tn < 4; ++tn)
#pragma unroll
            for (int r = 0; r < 4; ++r) macc[tm][tn][r] = -3e38f;

    for (int t = 0; t < ntiles; ++t) {
        __syncthreads();   // Xs/H1s reuse vs previous tile's reads
        // stage 64 rows fp32 -> bf16 (rows clamped to cnt-1)
#pragma unroll
        for (int i = 0; i < 4; ++i) {
            int c   = tid + 256 * i;
            int row = c >> 4;
            int cc  = (c & 15) * 8;
            int pr  = t * 64 + row;
            if (pr >= cnt) pr = cnt - 1;
            const float* src = X + (size_t)(s0 + pr) * SP_FEAT + cc;
            float4 u0 = *(const float4*)src;
            float4 u1 = *(const float4*)(src + 4);
            union { bf16x8 v; bf16 h[8]; } u;
            u.h[0] = __float2bfloat16(u0.x); u.h[1] = __float2bfloat16(u0.y);
            u.h[2] = __float2bfloat16(u0.z); u.h[3] = __float2bfloat16(u0.w);
            u.h[4] = __float2bfloat16(u1.x); u.h[5] = __float2bfloat16(u1.y);
            u.h[6] = __float2bfloat16(u1.z); u.h[7] = __float2bfloat16(u1.w);
            *(bf16x8*)(&Xs[row][cc]) = u.v;
        }
        __syncthreads();

        // GEMM1: wave w -> H1 cols [16w,16w+16), 64 rows, K=128
        floatx4 acc1[4] = {zero4, zero4, zero4, zero4};
#pragma unroll
        for (int ks = 0; ks < 4; ++ks) {
            int k = ks * 32 + quad * 8;
#pragma unroll
            for (int tm = 0; tm < 4; ++tm) {
                bf16x8 a = *(bf16x8*)(&Xs[16 * tm + l15][k]);
                acc1[tm] = __builtin_amdgcn_mfma_f32_16x16x32_bf16(a, bw1[ks], acc1[tm], 0, 0, 0);
            }
        }
#pragma unroll
        for (int tm = 0; tm < 4; ++tm) {
#pragma unroll
            for (int r = 0; r < 4; ++r) {
                float v = acc1[tm][r] + b1v;
                v = v > 0.f ? v : 0.f;
                H1s[16 * tm + quad * 4 + r][16 * w + l15] = __float2bfloat16(v);
            }
        }
        __syncthreads();

        // GEMM2: wave w -> cols [64w,64w+64); merge raw acc into running max
#pragma unroll
        for (int tm = 0; tm < 4; ++tm) {
            bf16x8 a0 = *(bf16x8*)(&H1s[16 * tm + l15][quad * 8]);
            bf16x8 a1 = *(bf16x8*)(&H1s[16 * tm + l15][32 + quad * 8]);
#pragma unroll
            for (int tn = 0; tn < 4; ++tn) {
                floatx4 acc = zero4;
                acc = __builtin_amdgcn_mfma_f32_16x16x32_bf16(a0, bf2[tn][0], acc, 0, 0, 0);
                acc = __builtin_amdgcn_mfma_f32_16x16x32_bf16(a1, bf2[tn][1], acc, 0, 0, 0);
#pragma unroll
                for (int r = 0; r < 4; ++r)
                    macc[tm][tn][r] = fmaxf(macc[tm][tn][r], acc[r]);
            }
        }
    }

    // reduce: per-lane over (tm,r), cross-lane over quad; bias+relu commute
#pragma unroll
    for (int tn = 0; tn < 4; ++tn) {
        float bst = -3e38f;
#pragma unroll
        for (int tm = 0; tm < 4; ++tm)
#pragma unroll
            for (int r = 0; r < 4; ++r) bst = fmaxf(bst, macc[tm][tn][r]);
        bst = fmaxf(bst, __shfl_xor(bst, 16, 64));
        bst = fmaxf(bst, __shfl_xor(bst, 32, 64));
        float v = bst + b2f[tn];
        v = v > 0.f ? v : 0.f;
        if (quad == 0) tokS[64 * w + 16 * tn + l15] = v;
    }
    __syncthreads();
    tok[(size_t)s * EMBED + tid] = tokS[tid];
}

// ---------------------------------------------------------------------------
// Scatter incl. zero padding (replaces the 67MB out-memset).
// grid = NUM_SP2*8; block b: group g=b>>3, rows [16*(b&7), +16) of 128
// virtual rows (0..63 remain slab, 64..127 mask slab).
// ---------------------------------------------------------------------------
__global__ __launch_bounds__(256) void scatter_kernel(
    const float* __restrict__ tok, const int* __restrict__ invR,
    const int* __restrict__ invM, float* __restrict__ out)
{
    const int g    = blockIdx.x >> 3;
    const int part = blockIdx.x & 7;
    const int tid  = threadIdx.x;
    float* outR = out + (size_t)g * PAD_LIMIT * EMBED;
    float* outM = out + (size_t)NUM_SP2 * PAD_LIMIT * EMBED + (size_t)g * PAD_LIMIT * EMBED;
#pragma unroll
    for (int rr = 0; rr < 16; ++rr) {
        int row = part * 16 + rr;
        if (row < PAD_LIMIT) {
            int sp = invR[g * PAD_LIMIT + row];
            float v = (sp >= 0) ? tok[(size_t)sp * EMBED + tid] : 0.f;
            outR[row * EMBED + tid] = v;
        } else {
            int r = row - PAD_LIMIT;
            int sp = invM[g * PAD_LIMIT + r];
            float v = (sp >= 0) ? tok[(size_t)sp * EMBED + tid] : 0.f;
            outM[r * EMBED + tid] = v;
        }
    }
}

// ---------------------------------------------------------------------------
extern "C" void kernel_launch(void* const* d_in, const int* in_sizes, int n_in,
                              void* d_out, int out_size, void* d_ws, size_t ws_size,
                              hipStream_t stream) {
    (void)in_sizes; (void)n_in; (void)ws_size; (void)out_size;
    const float* X        = (const float*)d_in[0];
    const int* idx10      = (const int*)d_in[1];
    const int* idx21      = (const int*)d_in[2];
    const void* is_masked = (const void*)d_in[3];
    const float* W1       = (const float*)d_in[4];
    const float* b1       = (const float*)d_in[5];
    const float* W2       = (const float*)d_in[6];
    const float* b2       = (const float*)d_in[7];
    float* out            = (float*)d_out;

    char* ws    = (char*)d_ws;
    float* tok  = (float*)ws;                                         // 4 MB
    bf16* W1t   = (bf16*)(ws + (size_t)NUM_SP * EMBED * 4);           // 16 KB
    bf16* W2t   = W1t + HIDDEN * SP_FEAT;                             // 32 KB
    int*  start = (int*)((char*)(W2t + EMBED * HIDDEN));              // 16.4 KB
    int*  invR  = start + (NUM_SP + 2);
    int*  invM  = invR + NUM_SP2 * PAD_LIMIT;                         // 2*64 KB

    const int prep_n = HIDDEN * SP_FEAT + EMBED * HIDDEN + NUM_SP + 1;
    prep_kernel<<<(prep_n + 255) / 256, 256, 0, stream>>>(W1, W2, idx10, W1t, W2t, start);
    rank_kernel<<<1, 256, 0, stream>>>(idx21, is_masked, invR, invM);
    mlp_segmax_kernel<<<NUM_SP, 256, 0, stream>>>(X, start, W1t, b1, W2t, b2, tok);
    scatter_kernel<<<NUM_SP2 * 8, 256, 0, stream>>>(tok, invR, invM, out);
}